// Round 6
// baseline (291.657 us; speedup 1.0000x reference)
//
#include <hip/hip_runtime.h>

#define H 32
#define SEQ 512
#define BM 16           // batch rows per block (= MFMA N)
#define NTHREADS 1024   // 16 waves; grid = 256 -> 1 block/CU, 4 waves/SIMD
#define HSTRIDE 40      // halves per h-row: 80B rows -> 16B-aligned b128 frags, 2-way banks

typedef _Float16 half8 __attribute__((ext_vector_type(8)));
typedef __attribute__((ext_vector_type(4))) float f32x4;

#define L2E 1.44269504088896340736f

__device__ __forceinline__ float rcp_(float x)  { return __builtin_amdgcn_rcpf(x); }
__device__ __forceinline__ float exp2_(float x) { return __builtin_amdgcn_exp2f(x); }  // raw v_exp_f32

__global__ __launch_bounds__(NTHREADS, 4) void lstm_kernel(
    const float* __restrict__ x,      // [4096,512]
    const float* __restrict__ w_ih0,  // [128,1]
    const float* __restrict__ w_hh0,  // [128,32]
    const float* __restrict__ b_ih0, const float* __restrict__ b_hh0,
    const float* __restrict__ w_ih1,  // [128,32]
    const float* __restrict__ w_hh1,  // [128,32]
    const float* __restrict__ b_ih1, const float* __restrict__ b_hh1,
    const float* __restrict__ fc1_w,  // [16,32]
    const float* __restrict__ fc1_b,  // [16]
    const float* __restrict__ fc2_w,  // [1,16]
    const float* __restrict__ fc2_b,  // [1]
    float* __restrict__ out)          // [4096]
{
    __shared__ __align__(16) float    xbufT[SEQ * BM];            // 32 KB, [step][row]
    __shared__ __align__(16) _Float16 h1s[2][BM * HSTRIDE];       // ping-pong h1 (fp16)
    __shared__ __align__(16) _Float16 h2s[2][BM * HSTRIDE];       // ping-pong h2 (fp16)
    __shared__ __align__(16) float    h2f[BM * 33];
    __shared__ __align__(16) float    yb[BM * 17];

    const int tid  = threadIdx.x;
    const int lane = tid & 63;
    const int wv   = tid >> 6;          // wave id 0..15
    const int grp  = wv >> 3;           // 0 = layer-1 waves, 1 = layer-2 waves
    const int tw   = wv & 7;            // tile index 0..7
    const int c    = lane & 15;         // frag free-index / batch col
    const int q    = lane >> 4;         // k-quad / D row-group
    const int r0   = blockIdx.x * BM;

    // ---- stage x transposed: xbufT[s][row]; 1024 threads, 8 steps each ----
    {
        const int row = tid >> 6;           // 0..15
        const int s0  = (tid & 63) * 8;     // 8 steps per thread
        const float* xr = x + (size_t)(r0 + row) * SEQ + s0;
        #pragma unroll
        for (int i = 0; i < 8; i += 4) {
            float4 v = *(const float4*)&xr[i];
            xbufT[(s0 + i + 0) * BM + row] = v.x;
            xbufT[(s0 + i + 1) * BM + row] = v.y;
            xbufT[(s0 + i + 2) * BM + row] = v.z;
            xbufT[(s0 + i + 3) * BM + row] = v.w;
        }
    }
    for (int i = tid; i < BM * HSTRIDE; i += NTHREADS) {
        h1s[0][i] = (_Float16)0.f; h1s[1][i] = (_Float16)0.f;
        h2s[0][i] = (_Float16)0.f; h2s[1][i] = (_Float16)0.f;
    }

    // ---- W fragments (A-operand), rows permuted r -> (gate r&3, unit 4*tw + r>>2) ----
    // gate scales folded (i,f,o: -log2e ; g: +2log2e) so EW uses raw v_exp_f32.
    const float gsc[4] = { -L2E, -L2E, 2.f * L2E, -L2E };
    const int worig = (c & 3) * H + 4 * tw + (c >> 2);
    const float wsc = gsc[c & 3];
    const int kb = 8 * q;
    const int m = c;
    const int u = 4 * tw + q;

    // fragment registers shared between the two disjoint wave groups
    half8 fA, fB, fC, fD;
    f32x4 biasv;
    float wx[4] = {0.f, 0.f, 0.f, 0.f};
    if (grp == 0) {
        const float* p = &w_hh0[worig * H + kb];
        #pragma unroll
        for (int j = 0; j < 8; ++j) { float v = p[j] * wsc; _Float16 h = (_Float16)v; fA[j] = h; fB[j] = (_Float16)(v - (float)h); }
        #pragma unroll
        for (int g = 0; g < 4; ++g) {
            biasv[g] = (b_ih0[g * H + u] + b_hh0[g * H + u]) * gsc[g];
            wx[g]    = w_ih0[g * H + u] * gsc[g];
        }
    } else {
        const float* p = &w_ih1[worig * H + kb];
        #pragma unroll
        for (int j = 0; j < 8; ++j) { float v = p[j] * wsc; _Float16 h = (_Float16)v; fA[j] = h; fB[j] = (_Float16)(v - (float)h); }
        p = &w_hh1[worig * H + kb];
        #pragma unroll
        for (int j = 0; j < 8; ++j) { float v = p[j] * wsc; _Float16 h = (_Float16)v; fC[j] = h; fD[j] = (_Float16)(v - (float)h); }
        #pragma unroll
        for (int g = 0; g < 4; ++g)
            biasv[g] = (b_ih1[g * H + u] + b_hh1[g * H + u]) * gsc[g];
    }

    float cst = 0.f, h2last = 0.f;

    const int fofs = c * HSTRIDE + kb;   // b128 frag read offset (halves)
    const int hofs = m * HSTRIDE + u;    // h write offset (halves)

    __syncthreads();

    // shared-rcp LSTM cell: 5 v_exp + 2 v_rcp
    auto cell = [&](const f32x4& g) -> float {
        float ei = exp2_(g[0]);
        float ef = exp2_(g[1]);
        float eg = exp2_(g[2]);
        float eo = exp2_(g[3]);
        float A  = 1.f + ei;
        float F  = 1.f + ef;
        float Gp = eg + 1.f, Gm = eg - 1.f;
        float t1 = A * Gp;
        float num = fmaf(cst, t1, Gm * F);
        float cn  = num * rcp_(F * t1);
        cn = __builtin_amdgcn_fmed3f(cn, -12.f, 12.f);
        cst = cn;
        float ec = exp2_(cn * (2.f * L2E));
        return (ec - 1.f) * rcp_((1.f + eo) * (ec + 1.f));
    };

    // iter t: L1 waves compute step t, L2 waves compute step t-1. 1 barrier/iter.
    auto do_step = [&](const _Float16* __restrict__ h1r, const _Float16* __restrict__ h2r,
                       _Float16* __restrict__ h1w, _Float16* __restrict__ h2w,
                       int t, bool e1, bool e2) {
        if (grp == 0) {
            if (e1) {
                half8 a1 = *(const half8*)(h1r + fofs);
                float xv = xbufT[t * BM + m];
                f32x4 g1 = biasv;
                g1 = __builtin_amdgcn_mfma_f32_16x16x32_f16(fA, a1, g1, 0, 0, 0);
                g1 = __builtin_amdgcn_mfma_f32_16x16x32_f16(fB, a1, g1, 0, 0, 0);
                #pragma unroll
                for (int j = 0; j < 4; ++j) g1[j] = fmaf(xv, wx[j], g1[j]);
                float h1v = cell(g1);
                h1w[hofs] = (_Float16)h1v;
            }
        } else {
            if (e2) {
                half8 a1 = *(const half8*)(h1r + fofs);
                half8 a2 = *(const half8*)(h2r + fofs);
                f32x4 ga = biasv;
                f32x4 gb = {0.f, 0.f, 0.f, 0.f};
                ga = __builtin_amdgcn_mfma_f32_16x16x32_f16(fA, a1, ga, 0, 0, 0);
                gb = __builtin_amdgcn_mfma_f32_16x16x32_f16(fC, a2, gb, 0, 0, 0);
                ga = __builtin_amdgcn_mfma_f32_16x16x32_f16(fB, a1, ga, 0, 0, 0);
                gb = __builtin_amdgcn_mfma_f32_16x16x32_f16(fD, a2, gb, 0, 0, 0);
                f32x4 g2;
                #pragma unroll
                for (int j = 0; j < 4; ++j) g2[j] = ga[j] + gb[j];
                float h2v = cell(g2);
                h2last = h2v;
                h2w[hofs] = (_Float16)h2v;
            }
        }
        __syncthreads();
    };

    do_step(h1s[0], h2s[0], h1s[1], h2s[1], 0, true, false);
    for (int tt = 0; tt < 255; ++tt) {
        int t = 1 + 2 * tt;
        do_step(h1s[1], h2s[1], h1s[0], h2s[0], t,     true, true);
        do_step(h1s[0], h2s[0], h1s[1], h2s[1], t + 1, true, true);
    }
    do_step(h1s[1], h2s[1], h1s[0], h2s[0], 511, true, true);
    do_step(h1s[0], h2s[0], h1s[1], h2s[1], 512, false, true);

    // ---- FC head: h2last lives in grp-1 lanes ----
    if (grp == 1) h2f[m * 33 + u] = h2last;
    __syncthreads();
    if (tid < BM * 16) {
        int rr = tid >> 4, j = tid & 15;
        float acc = fc1_b[j];
        #pragma unroll
        for (int k = 0; k < H; ++k) acc += fc1_w[j * H + k] * h2f[rr * 33 + k];
        acc = acc >= 0.f ? acc : 0.2f * acc;
        yb[rr * 17 + j] = acc * fc2_w[j];
    }
    __syncthreads();
    if (tid < BM) {
        float acc = fc2_b[0];
        #pragma unroll
        for (int j = 0; j < 16; ++j) acc += yb[tid * 17 + j];
        out[r0 + tid] = acc;
    }
}

extern "C" void kernel_launch(void* const* d_in, const int* in_sizes, int n_in,
                              void* d_out, int out_size, void* d_ws, size_t ws_size,
                              hipStream_t stream) {
    const float* x     = (const float*)d_in[0];
    const float* w_ih0 = (const float*)d_in[1];
    const float* w_hh0 = (const float*)d_in[2];
    const float* b_ih0 = (const float*)d_in[3];
    const float* b_hh0 = (const float*)d_in[4];
    const float* w_ih1 = (const float*)d_in[5];
    const float* w_hh1 = (const float*)d_in[6];
    const float* b_ih1 = (const float*)d_in[7];
    const float* b_hh1 = (const float*)d_in[8];
    const float* fc1_w = (const float*)d_in[9];
    const float* fc1_b = (const float*)d_in[10];
    const float* fc2_w = (const float*)d_in[11];
    const float* fc2_b = (const float*)d_in[12];
    float* out = (float*)d_out;

    const int B = in_sizes[0] / SEQ;   // 4096
    hipLaunchKernelGGL(lstm_kernel, dim3(B / BM), dim3(NTHREADS), 0, stream,
                       x, w_ih0, w_hh0, b_ih0, b_hh0, w_ih1, w_hh1, b_ih1, b_hh1,
                       fc1_w, fc1_b, fc2_w, fc2_b, out);
}